// Round 6
// baseline (961.226 us; speedup 1.0000x reference)
//
#include <hip/hip_runtime.h>
#include <hip/hip_bf16.h>

#define THRES 1.0f
#define DECAY 0.9375f

// ws layout (floats):
#define OFF_SIN    0u              // 20*12288   = 245760
#define OFF_D1     245760u         // 20*115200  = 2304000
#define OFF_SC1    2549760u        // 20*115200  = 2304000
#define OFF_D2     4853760u        // 19*200704  = 3813376
#define OFF_MASK   8667136u        // 200704 (u32)
#define OFF_PART   8867840u        // 896*152    = 136192
// total 9004032 floats = 36 MB

// ---------------- input layer: avgpool + IF (no decay) ----------------
__global__ void k_input(const float* __restrict__ image, float* __restrict__ s_in) {
    int idx = blockIdx.x * 256 + threadIdx.x;
    if (idx >= 12288) return;
    int c = idx >> 12;
    int p = idx & 4095;
    int y = p >> 6, x = p & 63;
    const float* b = image + c * 16384 + (2 * y) * 128 + 2 * x;
    float v = ((b[0] + b[1]) + (b[128] + b[129])) * 0.25f;
    float mp = 0.f;
    for (int t = 0; t < 20; ++t) {
        mp += v;
        float s = (mp >= THRES) ? 1.f : 0.f;
        s_in[t * 12288 + idx] = s;
        mp -= s;
    }
}

// ---------------- conv1 batched drive ----------------
// tasks: t(20) x og(16, 2 outs) x y(60) x xc(6, 10 px) = 115200
__global__ void k_conv1(const float* __restrict__ s_in, const float* __restrict__ w_c1,
                        float* __restrict__ D1) {
    int task = blockIdx.x * 256 + threadIdx.x;
    if (task >= 115200) return;
    int xc = task % 6;
    int tmp = task / 6;
    int y = tmp % 60; tmp /= 60;
    int og = tmp % 16;
    int t  = tmp / 16;
    int o0 = og * 2, x0 = xc * 10;
    float acc[2][10];
    #pragma unroll
    for (int o = 0; o < 2; ++o)
        #pragma unroll
        for (int x = 0; x < 10; ++x) acc[o][x] = 0.f;
    const float* inb = s_in + t * 12288;
    for (int c = 0; c < 3; ++c)
        #pragma unroll
        for (int ky = 0; ky < 5; ++ky) {
            float in[14];
            const float* row = inb + c * 4096 + (y + ky) * 64 + x0;
            #pragma unroll
            for (int i = 0; i < 14; ++i) in[i] = row[i];
            #pragma unroll
            for (int kx = 0; kx < 5; ++kx)
                #pragma unroll
                for (int o = 0; o < 2; ++o) {
                    float w = w_c1[((o0 + o) * 3 + c) * 25 + ky * 5 + kx];
                    #pragma unroll
                    for (int x = 0; x < 10; ++x) acc[o][x] += in[x + kx] * w;
                }
        }
    #pragma unroll
    for (int o = 0; o < 2; ++o)
        #pragma unroll
        for (int x = 0; x < 10; ++x)
            D1[((t * 32 + o0 + o) * 60 + y) * 60 + x0 + x] = acc[o][x];
}

// ---------------- conv1 LIF chain -> s_c1 ----------------
__global__ void k_lif1(const float* __restrict__ D1, float* __restrict__ s_c1) {
    int idx = blockIdx.x * 256 + threadIdx.x;
    if (idx >= 115200) return;
    float mp = 0.f;
    for (int t = 0; t < 20; ++t) {
        mp += D1[t * 115200 + idx];
        float s = (mp >= THRES) ? 1.f : 0.f;
        s_c1[t * 115200 + idx] = s;
        mp = (s != 0.f) ? (mp - THRES) : mp * DECAY;
    }
}

// ---------------- conv2 batched drive ----------------
// tasks: tp(19) x og(32, 2 outs) x y(56) x xc(7, 8 px) = 238336  (exactly 931*256)
__global__ void k_conv2(const float* __restrict__ s_c1, const float* __restrict__ w_c2,
                        float* __restrict__ D2) {
    int task = blockIdx.x * 256 + threadIdx.x;
    int xc = task % 7;
    int tmp = task / 7;
    int y = tmp % 56; tmp /= 56;
    int og = tmp % 32;
    int tp = tmp / 32;
    int o0 = og * 2, x0 = xc * 8;
    float acc[2][8];
    #pragma unroll
    for (int o = 0; o < 2; ++o)
        #pragma unroll
        for (int x = 0; x < 8; ++x) acc[o][x] = 0.f;
    const float* inb = s_c1 + tp * 115200;
    for (int c = 0; c < 32; ++c)
        #pragma unroll
        for (int ky = 0; ky < 5; ++ky) {
            float in[12];
            const float* row = inb + c * 3600 + (y + ky) * 60 + x0;
            #pragma unroll
            for (int i = 0; i < 12; ++i) in[i] = row[i];
            #pragma unroll
            for (int kx = 0; kx < 5; ++kx)
                #pragma unroll
                for (int o = 0; o < 2; ++o) {
                    float w = w_c2[((o0 + o) * 32 + c) * 25 + ky * 5 + kx];
                    #pragma unroll
                    for (int x = 0; x < 8; ++x) acc[o][x] += in[x + kx] * w;
                }
        }
    #pragma unroll
    for (int o = 0; o < 2; ++o)
        #pragma unroll
        for (int x = 0; x < 8; ++x)
            D2[((tp * 64 + o0 + o) * 56 + y) * 56 + x0 + x] = acc[o][x];
}

// ---------------- conv2 LIF chain -> packed spike masks ----------------
__global__ void k_lif2(const float* __restrict__ D2, unsigned int* __restrict__ mask) {
    int idx = blockIdx.x * 256 + threadIdx.x;
    if (idx >= 200704) return;
    float mp = 0.f;
    unsigned int m = 0u;
    for (int u = 1; u < 20; ++u) {
        mp += D2[(u - 1) * 200704 + idx];
        float s = (mp >= THRES) ? 1.f : 0.f;
        if (s != 0.f) m |= (1u << u);
        mp = (s != 0.f) ? (mp - THRES) : mp * DECAY;
    }
    mask[idx] = m;
}

// ---------------- linear1 GEMM: 8 rows/block x 14 j-splits ----------------
// Z[i][k] = sum_j W[i][j]*spikebit(k of mask[j]), k=0..18
__global__ void __launch_bounds__(256) k_gemm(const float* __restrict__ W,
                                              const unsigned int* __restrict__ mask,
                                              float* __restrict__ partials) {
    int rg = blockIdx.x / 14, js = blockIdx.x % 14;
    int i0 = rg * 8;
    size_t j0 = (size_t)js * 14336;
    int tid = threadIdx.x;
    float acc[8][19];
    #pragma unroll
    for (int r = 0; r < 8; ++r)
        #pragma unroll
        for (int t = 0; t < 19; ++t) acc[r][t] = 0.f;

    const float* Wb = W + (size_t)i0 * 200704 + j0;
    const unsigned int* M = mask + j0;

    for (int it = 0; it < 14; ++it) {
        int j = (it * 256 + tid) * 4;
        uint4 m4 = *(const uint4*)(M + j);
        float4 a[8];
        #pragma unroll
        for (int r = 0; r < 8; ++r)
            a[r] = *(const float4*)(Wb + (size_t)r * 200704 + j);
        float av[8][4];
        #pragma unroll
        for (int r = 0; r < 8; ++r) {
            av[r][0] = a[r].x; av[r][1] = a[r].y; av[r][2] = a[r].z; av[r][3] = a[r].w;
        }
        unsigned int mm[4] = {m4.x, m4.y, m4.z, m4.w};
        #pragma unroll
        for (int jj = 0; jj < 4; ++jj) {
            unsigned int m = mm[jj];
            #pragma unroll
            for (int t = 0; t < 19; ++t) {
                float s = (float)((m >> t) & 1u);
                #pragma unroll
                for (int r = 0; r < 8; ++r) acc[r][t] += av[r][jj] * s;
            }
        }
    }

    __shared__ float red[4][152];
    int wv = tid >> 6, ln = tid & 63;
    #pragma unroll
    for (int r = 0; r < 8; ++r)
        #pragma unroll
        for (int t = 0; t < 19; ++t) {
            float v = acc[r][t];
            v += __shfl_xor(v, 32);
            v += __shfl_xor(v, 16);
            v += __shfl_xor(v, 8);
            v += __shfl_xor(v, 4);
            v += __shfl_xor(v, 2);
            v += __shfl_xor(v, 1);
            if (ln == 0) red[wv][r * 19 + t] = v;
        }
    __syncthreads();
    if (tid < 152)
        partials[(size_t)blockIdx.x * 152 + tid] =
            red[0][tid] + red[1][tid] + red[2][tid] + red[3][tid];
}

// ---------------- head: reduce partials + l1 LIF + l2 matvec + l2 LIF -> out -------
__global__ void k_head(const float* __restrict__ partials, const float* __restrict__ w_l2,
                       float* __restrict__ out) {
    __shared__ float sl1[20][512];
    __shared__ float d2s[20][10];
    int tid = threadIdx.x;          // 512 threads, one l1 neuron each
    int rg = tid >> 3, r = tid & 7;
    float z[19];
    #pragma unroll
    for (int k = 0; k < 19; ++k) {
        float s = 0.f;
        for (int js = 0; js < 14; ++js)
            s += partials[(size_t)(rg * 14 + js) * 152 + r * 19 + k];
        z[k] = s;
    }
    {
        float mp = 0.f;
        sl1[0][tid] = 0.f;
        for (int u = 1; u < 20; ++u) {
            mp += z[u - 1];
            float s = (mp >= THRES) ? 1.f : 0.f;
            sl1[u][tid] = s;
            mp = (s != 0.f) ? (mp - THRES) : mp * DECAY;
        }
    }
    __syncthreads();
    int wv = tid >> 6, ln = tid & 63;
    for (int task = wv; task < 190; task += 8) {
        int u = task / 10 + 1;
        int o = task % 10;
        float p = 0.f;
        for (int ii = ln; ii < 512; ii += 64) p += w_l2[o * 512 + ii] * sl1[u - 1][ii];
        p += __shfl_xor(p, 32);
        p += __shfl_xor(p, 16);
        p += __shfl_xor(p, 8);
        p += __shfl_xor(p, 4);
        p += __shfl_xor(p, 2);
        p += __shfl_xor(p, 1);
        if (ln == 0) d2s[u][o] = p;
    }
    __syncthreads();
    if (tid < 10) {
        out[tid] = 0.f;
        out[10 + tid] = 0.f;
        float mp = 0.f;
        for (int u = 1; u < 20; ++u) {
            mp += d2s[u][tid];
            float s = (mp >= THRES) ? 1.f : 0.f;
            out[(u + 1) * 10 + tid] = s;
            mp = (s != 0.f) ? (mp - THRES) : mp * DECAY;
        }
    }
}

extern "C" void kernel_launch(void* const* d_in, const int* in_sizes, int n_in,
                              void* d_out, int out_size, void* d_ws, size_t ws_size,
                              hipStream_t stream) {
    const float* image = (const float*)d_in[0];
    const float* w_c1  = (const float*)d_in[1];
    const float* w_c2  = (const float*)d_in[2];
    const float* w_l1  = (const float*)d_in[3];
    const float* w_l2  = (const float*)d_in[4];
    float* out = (float*)d_out;
    float* ws  = (float*)d_ws;

    float*        s_in  = ws + OFF_SIN;
    float*        D1    = ws + OFF_D1;
    float*        s_c1  = ws + OFF_SC1;
    float*        D2    = ws + OFF_D2;
    unsigned int* mask  = (unsigned int*)(ws + OFF_MASK);
    float*        part  = ws + OFF_PART;

    k_input <<<48,  256, 0, stream>>>(image, s_in);
    k_conv1 <<<450, 256, 0, stream>>>(s_in, w_c1, D1);
    k_lif1  <<<450, 256, 0, stream>>>(D1, s_c1);
    k_conv2 <<<931, 256, 0, stream>>>(s_c1, w_c2, D2);
    k_lif2  <<<784, 256, 0, stream>>>(D2, mask);
    k_gemm  <<<896, 256, 0, stream>>>(w_l1, mask, part);
    k_head  <<<1,   512, 0, stream>>>(part, w_l2, out);
}

// Round 7
// 770.587 us; speedup vs baseline: 1.2474x; 1.2474x over previous
//
#include <hip/hip_runtime.h>
#include <hip/hip_bf16.h>

#define THRES 1.0f
#define DECAY 0.9375f

// ws layout (floats):
#define OFF_SIN    0u              // 20*12288   = 245760
#define OFF_D1     245760u         // 20*115200  = 2304000
#define OFF_SC1    2549760u        // 20*115200  = 2304000
#define OFF_D2     4853760u        // 19*200704  = 3813376
#define OFF_MASK   8667136u        // 200704 (u32)
#define OFF_PART   8867840u        // 1792*76    = 136192
// total 9004032 floats = 36 MB

// ---------------- input layer: avgpool + IF (no decay) ----------------
__global__ void k_input(const float* __restrict__ image, float* __restrict__ s_in) {
    int idx = blockIdx.x * 256 + threadIdx.x;
    if (idx >= 12288) return;
    int c = idx >> 12;
    int p = idx & 4095;
    int y = p >> 6, x = p & 63;
    const float* b = image + c * 16384 + (2 * y) * 128 + 2 * x;
    float v = ((b[0] + b[1]) + (b[128] + b[129])) * 0.25f;
    float mp = 0.f;
    for (int t = 0; t < 20; ++t) {
        mp += v;
        float s = (mp >= THRES) ? 1.f : 0.f;
        s_in[t * 12288 + idx] = s;
        mp -= s;
    }
}

// ---------------- conv1 batched drive ----------------
// grid: t(20) x o(32) = 640 blocks; block 384 thr: y(60) x xc(6, 10 px) = 360 active
// o from blockIdx -> weight addresses wave-uniform -> scalar loads
__global__ void __launch_bounds__(384) k_conv1(const float* __restrict__ s_in,
                                               const float* __restrict__ w_c1,
                                               float* __restrict__ D1) {
    int bid = blockIdx.x;
    int t = bid >> 5, o = bid & 31;
    int task = threadIdx.x;
    if (task >= 360) return;
    int y = task / 6, xc = task % 6;
    int x0 = xc * 10;
    float acc[10];
    #pragma unroll
    for (int x = 0; x < 10; ++x) acc[x] = 0.f;
    const float* inb = s_in + t * 12288;
    for (int c = 0; c < 3; ++c)
        #pragma unroll
        for (int ky = 0; ky < 5; ++ky) {
            float in[14];
            const float* row = inb + c * 4096 + (y + ky) * 64 + x0;
            #pragma unroll
            for (int i = 0; i < 14; ++i) in[i] = row[i];
            #pragma unroll
            for (int kx = 0; kx < 5; ++kx) {
                float w = w_c1[(o * 3 + c) * 25 + ky * 5 + kx];   // uniform -> s_load
                #pragma unroll
                for (int x = 0; x < 10; ++x) acc[x] += in[x + kx] * w;
            }
        }
    #pragma unroll
    for (int x = 0; x < 10; ++x)
        D1[((t * 32 + o) * 60 + y) * 60 + x0 + x] = acc[x];
}

// ---------------- conv1 LIF chain -> s_c1 ----------------
__global__ void k_lif1(const float* __restrict__ D1, float* __restrict__ s_c1) {
    int idx = blockIdx.x * 256 + threadIdx.x;
    if (idx >= 115200) return;
    float mp = 0.f;
    for (int t = 0; t < 20; ++t) {
        mp += D1[t * 115200 + idx];
        float s = (mp >= THRES) ? 1.f : 0.f;
        s_c1[t * 115200 + idx] = s;
        mp = (s != 0.f) ? (mp - THRES) : mp * DECAY;
    }
}

// ---------------- conv2 batched drive ----------------
// grid: tp(19) x og(32) = 608 blocks; block 448 thr: y(56) x xq(8, 7 px) = 448 active
// og from blockIdx -> 2 output channels, weight addresses wave-uniform
__global__ void __launch_bounds__(448) k_conv2(const float* __restrict__ s_c1,
                                               const float* __restrict__ w_c2,
                                               float* __restrict__ D2) {
    int bid = blockIdx.x;
    int tp = bid >> 5, og = bid & 31;
    int task = threadIdx.x;
    int y = task >> 3, xq = task & 7;
    int o0 = og * 2, x0 = xq * 7;
    float acc[2][7];
    #pragma unroll
    for (int o = 0; o < 2; ++o)
        #pragma unroll
        for (int x = 0; x < 7; ++x) acc[o][x] = 0.f;
    const float* inb = s_c1 + tp * 115200;
    for (int c = 0; c < 32; ++c)
        #pragma unroll
        for (int ky = 0; ky < 5; ++ky) {
            float in[11];
            const float* row = inb + c * 3600 + (y + ky) * 60 + x0;
            #pragma unroll
            for (int i = 0; i < 11; ++i) in[i] = row[i];
            #pragma unroll
            for (int kx = 0; kx < 5; ++kx)
                #pragma unroll
                for (int o = 0; o < 2; ++o) {
                    float w = w_c2[((o0 + o) * 32 + c) * 25 + ky * 5 + kx]; // uniform -> s_load
                    #pragma unroll
                    for (int x = 0; x < 7; ++x) acc[o][x] += in[x + kx] * w;
                }
        }
    #pragma unroll
    for (int o = 0; o < 2; ++o)
        #pragma unroll
        for (int x = 0; x < 7; ++x)
            D2[((tp * 64 + o0 + o) * 56 + y) * 56 + x0 + x] = acc[o][x];
}

// ---------------- conv2 LIF chain -> packed spike masks ----------------
__global__ void k_lif2(const float* __restrict__ D2, unsigned int* __restrict__ mask) {
    int idx = blockIdx.x * 256 + threadIdx.x;
    if (idx >= 200704) return;
    float mp = 0.f;
    unsigned int m = 0u;
    for (int u = 1; u < 20; ++u) {
        mp += D2[(u - 1) * 200704 + idx];
        float s = (mp >= THRES) ? 1.f : 0.f;
        if (s != 0.f) m |= (1u << u);
        mp = (s != 0.f) ? (mp - THRES) : mp * DECAY;
    }
    mask[idx] = m;
}

// ---------------- linear1 GEMM: 4 rows/block x 14 j-splits, rolling prefetch ------
// Z[i][k] = sum_j W[i][j]*spikebit(k of mask[j]), k=0..18
__global__ void __launch_bounds__(256) k_gemm(const float* __restrict__ W,
                                              const unsigned int* __restrict__ mask,
                                              float* __restrict__ partials) {
    int rg = blockIdx.x / 14, js = blockIdx.x % 14;
    int i0 = rg * 4;
    size_t j0 = (size_t)js * 14336;
    int tid = threadIdx.x;
    float acc[4][19];
    #pragma unroll
    for (int r = 0; r < 4; ++r)
        #pragma unroll
        for (int t = 0; t < 19; ++t) acc[r][t] = 0.f;

    const float* W0 = W + (size_t)(i0 + 0) * 200704 + j0;
    const float* W1 = W + (size_t)(i0 + 1) * 200704 + j0;
    const float* W2 = W + (size_t)(i0 + 2) * 200704 + j0;
    const float* W3 = W + (size_t)(i0 + 3) * 200704 + j0;
    const unsigned int* M = mask + j0;

    int jc = tid * 4;
    uint4  mc = *(const uint4*)(M + jc);
    float4 c0 = *(const float4*)(W0 + jc);
    float4 c1 = *(const float4*)(W1 + jc);
    float4 c2 = *(const float4*)(W2 + jc);
    float4 c3 = *(const float4*)(W3 + jc);

    for (int it = 0; it < 14; ++it) {
        uint4 mn; float4 n0, n1, n2, n3;
        if (it < 13) {                      // issue next-iter loads before consuming
            int jn = ((it + 1) * 256 + tid) * 4;
            mn = *(const uint4*)(M + jn);
            n0 = *(const float4*)(W0 + jn);
            n1 = *(const float4*)(W1 + jn);
            n2 = *(const float4*)(W2 + jn);
            n3 = *(const float4*)(W3 + jn);
        }
        unsigned int mm[4] = {mc.x, mc.y, mc.z, mc.w};
        float a0[4] = {c0.x, c0.y, c0.z, c0.w};
        float a1[4] = {c1.x, c1.y, c1.z, c1.w};
        float a2[4] = {c2.x, c2.y, c2.z, c2.w};
        float a3[4] = {c3.x, c3.y, c3.z, c3.w};
        #pragma unroll
        for (int jj = 0; jj < 4; ++jj) {
            unsigned int m = mm[jj];
            #pragma unroll
            for (int t = 0; t < 19; ++t) {
                float s = (float)((m >> t) & 1u);
                acc[0][t] += a0[jj] * s;
                acc[1][t] += a1[jj] * s;
                acc[2][t] += a2[jj] * s;
                acc[3][t] += a3[jj] * s;
            }
        }
        if (it < 13) { mc = mn; c0 = n0; c1 = n1; c2 = n2; c3 = n3; }
    }

    __shared__ float red[4][76];
    int wv = tid >> 6, ln = tid & 63;
    #pragma unroll
    for (int r = 0; r < 4; ++r)
        #pragma unroll
        for (int t = 0; t < 19; ++t) {
            float v = acc[r][t];
            v += __shfl_xor(v, 32);
            v += __shfl_xor(v, 16);
            v += __shfl_xor(v, 8);
            v += __shfl_xor(v, 4);
            v += __shfl_xor(v, 2);
            v += __shfl_xor(v, 1);
            if (ln == 0) red[wv][r * 19 + t] = v;
        }
    __syncthreads();
    if (tid < 76)
        partials[(size_t)blockIdx.x * 76 + tid] =
            red[0][tid] + red[1][tid] + red[2][tid] + red[3][tid];
}

// ---------------- head: reduce partials + l1 LIF + l2 matvec + l2 LIF -> out -------
__global__ void k_head(const float* __restrict__ partials, const float* __restrict__ w_l2,
                       float* __restrict__ out) {
    __shared__ float sl1[20][512];
    __shared__ float d2s[20][10];
    int tid = threadIdx.x;          // 512 threads, one l1 neuron each
    int rg = tid >> 2, r = tid & 3; // 128 rowgroups x 4 rows
    float z[19];
    #pragma unroll
    for (int k = 0; k < 19; ++k) {
        float s = 0.f;
        for (int js = 0; js < 14; ++js)
            s += partials[(size_t)(rg * 14 + js) * 76 + r * 19 + k];
        z[k] = s;
    }
    {
        float mp = 0.f;
        sl1[0][tid] = 0.f;
        for (int u = 1; u < 20; ++u) {
            mp += z[u - 1];
            float s = (mp >= THRES) ? 1.f : 0.f;
            sl1[u][tid] = s;
            mp = (s != 0.f) ? (mp - THRES) : mp * DECAY;
        }
    }
    __syncthreads();
    int wv = tid >> 6, ln = tid & 63;
    for (int task = wv; task < 190; task += 8) {
        int u = task / 10 + 1;
        int o = task % 10;
        float p = 0.f;
        for (int ii = ln; ii < 512; ii += 64) p += w_l2[o * 512 + ii] * sl1[u - 1][ii];
        p += __shfl_xor(p, 32);
        p += __shfl_xor(p, 16);
        p += __shfl_xor(p, 8);
        p += __shfl_xor(p, 4);
        p += __shfl_xor(p, 2);
        p += __shfl_xor(p, 1);
        if (ln == 0) d2s[u][o] = p;
    }
    __syncthreads();
    if (tid < 10) {
        out[tid] = 0.f;
        out[10 + tid] = 0.f;
        float mp = 0.f;
        for (int u = 1; u < 20; ++u) {
            mp += d2s[u][tid];
            float s = (mp >= THRES) ? 1.f : 0.f;
            out[(u + 1) * 10 + tid] = s;
            mp = (s != 0.f) ? (mp - THRES) : mp * DECAY;
        }
    }
}

extern "C" void kernel_launch(void* const* d_in, const int* in_sizes, int n_in,
                              void* d_out, int out_size, void* d_ws, size_t ws_size,
                              hipStream_t stream) {
    const float* image = (const float*)d_in[0];
    const float* w_c1  = (const float*)d_in[1];
    const float* w_c2  = (const float*)d_in[2];
    const float* w_l1  = (const float*)d_in[3];
    const float* w_l2  = (const float*)d_in[4];
    float* out = (float*)d_out;
    float* ws  = (float*)d_ws;

    float*        s_in  = ws + OFF_SIN;
    float*        D1    = ws + OFF_D1;
    float*        s_c1  = ws + OFF_SC1;
    float*        D2    = ws + OFF_D2;
    unsigned int* mask  = (unsigned int*)(ws + OFF_MASK);
    float*        part  = ws + OFF_PART;

    k_input <<<48,   256, 0, stream>>>(image, s_in);
    k_conv1 <<<640,  384, 0, stream>>>(s_in, w_c1, D1);
    k_lif1  <<<450,  256, 0, stream>>>(D1, s_c1);
    k_conv2 <<<608,  448, 0, stream>>>(s_c1, w_c2, D2);
    k_lif2  <<<784,  256, 0, stream>>>(D2, mask);
    k_gemm  <<<1792, 256, 0, stream>>>(w_l1, mask, part);
    k_head  <<<1,    512, 0, stream>>>(part, w_l2, out);
}